// Round 4
// baseline (2004.699 us; speedup 1.0000x reference)
//
#include <hip/hip_runtime.h>
#include <stdint.h>

// EISNUCell, f32 I/O. B=8192, N_IN=512, N_UNITS=2048, N_EXC=1024.
//
// pre_exc[b,j] = sum_k x_t[b,k] iw[k,j]      + y_exc[b,j] + sum_k y_inh[b,k] eiw[k,j]
//             + l[j]*s_exc[b,j]*(1-y_exc[b,j])                         (j < 1024)
// pre_inh[b,j] = sum_k x_t[b,k] iw[k,1024+j] + y_inh[b,j] - sum_k y_exc[b,k] eiw[j,k]
//             + l[1024+j]*s_inh[b,j]*(1-y_inh[b,j])
// s_new = relu(pre); y_new = (s_new + b > 0) ? 1 : 0
//
// Round-3 status: output 0 PASSED (GEMM + dtype detection + f64 tie-fixup all
// verified). Output 1 failed only because eisnu_fixup wrote s to chunk
// (half?1:3) -- transposed. This round: fix that one line ((half?3:1)).

__device__ __forceinline__ float bf2f(unsigned short u) {
  union { unsigned u; float f; } v; v.u = ((unsigned)u) << 16; return v.f;
}
__device__ __forceinline__ unsigned short f2bf(float f) {
  union { float f; unsigned u; } v; v.f = f;
  unsigned x = v.u;
  return (unsigned short)((x + 0x7fffu + ((x >> 16) & 1u)) >> 16);
}

__device__ __forceinline__ float ldf(const void* p, size_t i, bool f32m) {
  return f32m ? ((const float*)p)[i] : bf2f(((const unsigned short*)p)[i]);
}
__device__ __forceinline__ void stf(void* p, size_t i, bool f32m, float v) {
  if (f32m) ((float*)p)[i] = v;
  else ((unsigned short*)p)[i] = f2bf(v);
}

__device__ __forceinline__ bool detect_f32(const void* yexc) {
  const unsigned short* p = (const unsigned short*)yexc;
  int cnt = 0;
  for (int i = 0; i < 256; i++) {
    float v = bf2f(p[i]);
    if (!(v >= -1.5f && v <= 1.5f)) cnt++;
  }
  return cnt >= 8;
}

__device__ __forceinline__ void ld8(const void* p, size_t elemOff, bool f32m, float* dst) {
  if (f32m) {
    const float4* q = (const float4*)((const float*)p + elemOff);
    float4 a = q[0], b = q[1];
    dst[0] = a.x; dst[1] = a.y; dst[2] = a.z; dst[3] = a.w;
    dst[4] = b.x; dst[5] = b.y; dst[6] = b.z; dst[7] = b.w;
  } else {
    const ushort4* q = (const ushort4*)((const unsigned short*)p + elemOff);
    ushort4 a = q[0], b = q[1];
    dst[0] = bf2f(a.x); dst[1] = bf2f(a.y); dst[2] = bf2f(a.z); dst[3] = bf2f(a.w);
    dst[4] = bf2f(b.x); dst[5] = bf2f(b.y); dst[6] = bf2f(b.z); dst[7] = bf2f(b.w);
  }
}

__global__ void ws_zero(int* wscnt) {
  if (threadIdx.x == 0 && blockIdx.x == 0) *wscnt = 0;
}

__global__ __launch_bounds__(256) void eisnu_gemm(
    const void* __restrict__ x_t, const void* __restrict__ y_exc,
    const void* __restrict__ s_exc, const void* __restrict__ y_inh,
    const void* __restrict__ s_inh, const void* __restrict__ iw,
    const void* __restrict__ eiw, const void* __restrict__ bvec,
    const void* __restrict__ lvec, void* __restrict__ out,
    int* wscnt, int* wslist, int cap) {
  __shared__ float As[128 * 21];   // [m][k] stride 21
  __shared__ float Bbuf[128 * 21]; // phase Bs [k][n] stride 128, or BsT [n][k] stride 21
  __shared__ int flagSh;

  const int t = threadIdx.x;
  if (t == 0) flagSh = detect_f32(y_exc) ? 1 : 0;
  __syncthreads();
  const bool f32m = flagSh != 0;

  const int tx = t & 15;   // n sub-tile
  const int ty = t >> 4;   // m sub-tile / Bs k-row
  const int n0 = blockIdx.x * 128;
  const int m0 = blockIdx.y * 128;
  const bool exc = (n0 < 1024);
  const int ar = t >> 1;        // A/BsT staging row (0..127)
  const int ak = (t & 1) * 8;   // staging k offset

  float acc[8][8];
#pragma unroll
  for (int i = 0; i < 8; i++)
#pragma unroll
    for (int j = 0; j < 8; j++) acc[i][j] = 0.f;

#pragma unroll 1
  for (int phase = 0; phase < 2; phase++) {
    const void* A; const void* B;
    int K, lda, ldb, ncol;
    if (phase == 0)      { A = x_t;   K = 512;  lda = 512;  B = iw;  ldb = 2048; ncol = n0; }
    else if (exc)        { A = y_inh; K = 1024; lda = 1024; B = eiw; ldb = 1024; ncol = n0; }
    else                 { A = y_exc; K = 1024; lda = 1024; B = eiw; ldb = 1024; ncol = n0 - 1024; }
    const bool bt = (phase == 1) && !exc;  // B accessed as rows eiw[n][k], negated

#pragma unroll 1
    for (int k0 = 0; k0 < K; k0 += 16) {
      float v8[8];
      ld8(A, (size_t)(m0 + ar) * lda + k0 + ak, f32m, v8);
#pragma unroll
      for (int q = 0; q < 8; q++) As[ar * 21 + ak + q] = v8[q];
      if (!bt) {
        ld8(B, (size_t)(k0 + ty) * ldb + ncol + tx * 8, f32m, v8);
#pragma unroll
        for (int q = 0; q < 8; q++) Bbuf[ty * 128 + tx * 8 + q] = v8[q];
      } else {
        ld8(B, (size_t)(ncol + ar) * ldb + k0 + ak, f32m, v8);
#pragma unroll
        for (int q = 0; q < 8; q++) Bbuf[ar * 21 + ak + q] = -v8[q];
      }
      __syncthreads();

#pragma unroll
      for (int kk = 0; kk < 16; kk++) {
        float av[8], bv[8];
#pragma unroll
        for (int i = 0; i < 8; i++) av[i] = As[(ty * 8 + i) * 21 + kk];
        if (!bt) {
#pragma unroll
          for (int j = 0; j < 8; j++) bv[j] = Bbuf[kk * 128 + tx * 8 + j];
        } else {
#pragma unroll
          for (int j = 0; j < 8; j++) bv[j] = Bbuf[(tx * 8 + j) * 21 + kk];
        }
#pragma unroll
        for (int i = 0; i < 8; i++)
#pragma unroll
          for (int j = 0; j < 8; j++) acc[i][j] = fmaf(av[i], bv[j], acc[i][j]);
      }
      __syncthreads();
    }
  }

  // ---- epilogue ----
  const void* yE = exc ? y_exc : y_inh;
  const void* sE = exc ? s_exc : s_inh;
  const size_t CH = 8388608ull;  // 8192*1024 elements per output chunk
  const size_t offY = (size_t)(exc ? 0 : 2) * CH;
  const size_t offS = (size_t)(exc ? 1 : 3) * CH;
  const int jb = (exc ? n0 : n0 - 1024) + tx * 8;

#pragma unroll
  for (int i = 0; i < 8; i++) {
    const int grow = m0 + ty * 8 + i;
#pragma unroll
    for (int j = 0; j < 8; j++) {
      const int jn = jb + j;
      const int gcol = n0 + tx * 8 + j;
      const size_t idx = (size_t)grow * 1024 + jn;
      const float yv = ldf(yE, idx, f32m);
      const float sv = ldf(sE, idx, f32m);
      const float lf = ldf(lvec, gcol, f32m);
      const float bb = ldf(bvec, gcol, f32m);
      const float pre = acc[i][j] + yv + lf * sv * (1.0f - yv);
      const float sn = fmaxf(pre, 0.0f);
      stf(out, offS + idx, f32m, sn);
      stf(out, offY + idx, f32m, (sn + bb > 0.0f) ? 1.0f : 0.0f);
      if (cap > 0 && fabsf(pre) < 1e-3f) {
        int slot = atomicAdd(wscnt, 1);
        if (slot < cap) wslist[slot] = (int)idx | ((exc ? 0 : 1) << 24);
      }
    }
  }
}

__global__ __launch_bounds__(256) void eisnu_fixup(
    const void* __restrict__ x_t, const void* __restrict__ y_exc,
    const void* __restrict__ s_exc, const void* __restrict__ y_inh,
    const void* __restrict__ s_inh, const void* __restrict__ iw,
    const void* __restrict__ eiw, const void* __restrict__ bvec,
    const void* __restrict__ lvec, void* __restrict__ out,
    const int* wscnt, const int* wslist, int cap) {
  __shared__ double red[256];
  __shared__ int flagSh;
  if (threadIdx.x == 0) flagSh = detect_f32(y_exc) ? 1 : 0;
  __syncthreads();
  const bool f32m = flagSh != 0;

  int count = *wscnt;
  if (count > cap) count = cap;

  for (int it = blockIdx.x; it < count; it += gridDim.x) {
    const int item = wslist[it];
    const int half = (item >> 24) & 1;  // 0 = exc, 1 = inh
    const size_t idx = (size_t)(item & 0xFFFFFF);
    const int bb = (int)(idx >> 10);
    const int j = (int)(idx & 1023);
    const int gcol = j + (half << 10);

    double part = 0.0;
    for (int k = threadIdx.x; k < 512; k += 256)
      part += (double)ldf(x_t, (size_t)bb * 512 + k, f32m) *
              (double)ldf(iw, (size_t)k * 2048 + gcol, f32m);
    if (half == 0) {
      for (int k = threadIdx.x; k < 1024; k += 256)
        part += (double)ldf(y_inh, (size_t)bb * 1024 + k, f32m) *
                (double)ldf(eiw, (size_t)k * 1024 + j, f32m);
    } else {
      for (int k = threadIdx.x; k < 1024; k += 256)
        part -= (double)ldf(y_exc, (size_t)bb * 1024 + k, f32m) *
                (double)ldf(eiw, (size_t)j * 1024 + k, f32m);
    }
    red[threadIdx.x] = part;
    __syncthreads();
    for (int s = 128; s > 0; s >>= 1) {
      if (threadIdx.x < s) red[threadIdx.x] += red[threadIdx.x + s];
      __syncthreads();
    }
    if (threadIdx.x == 0) {
      const void* yH = half ? y_inh : y_exc;
      const void* sH = half ? s_inh : s_exc;
      const double yv = ldf(yH, idx, f32m);
      const double sv = ldf(sH, idx, f32m);
      const double lv = ldf(lvec, gcol, f32m);
      const double bv = ldf(bvec, gcol, f32m);
      const double pre = red[0] + yv + lv * sv * (1.0 - yv);
      const double sn = pre > 0.0 ? pre : 0.0;
      const size_t CH = 8388608ull;
      stf(out, (size_t)(half ? 2 : 0) * CH + idx, f32m, (sn + bv > 0.0) ? 1.0f : 0.0f);
      stf(out, (size_t)(half ? 3 : 1) * CH + idx, f32m, (float)sn);  // FIXED: was (half?1:3)
    }
    __syncthreads();
  }
}

extern "C" void kernel_launch(void* const* d_in, const int* in_sizes, int n_in,
                              void* d_out, int out_size, void* d_ws, size_t ws_size,
                              hipStream_t stream) {
  const void* x_t   = d_in[0];
  const void* y_exc = d_in[1];
  const void* s_exc = d_in[2];
  const void* y_inh = d_in[3];
  const void* s_inh = d_in[4];
  const void* iw    = d_in[5];
  const void* eiw   = d_in[6];
  const void* b     = d_in[7];
  const void* lv    = d_in[8];

  int* wscnt = (int*)d_ws;
  int* wslist = wscnt ? wscnt + 2 : nullptr;
  const int cap = (d_ws != nullptr && ws_size >= (1u << 20)) ? 65536 : 0;

  if (cap > 0) ws_zero<<<1, 64, 0, stream>>>(wscnt);
  eisnu_gemm<<<dim3(16, 64), 256, 0, stream>>>(
      x_t, y_exc, s_exc, y_inh, s_inh, iw, eiw, b, lv, d_out, wscnt, wslist, cap);
  if (cap > 0)
    eisnu_fixup<<<dim3(256), 256, 0, stream>>>(
        x_t, y_exc, s_exc, y_inh, s_inh, iw, eiw, b, lv, d_out, wscnt, wslist, cap);
}

// Round 5
// 703.317 us; speedup vs baseline: 2.8503x; 2.8503x over previous
//
#include <hip/hip_runtime.h>
#include <stdint.h>

// EISNUCell, f32 I/O (proven round 4). B=8192, N_IN=512, N_UNITS=2048, N_EXC=1024.
//
// pre_exc[b,j] = x_t.iw[:, j<1024] + y_exc + y_inh.eiw     + l*s_exc*(1-y_exc)
// pre_inh[b,j] = x_t.iw[:, 1024+j] + y_inh - y_exc.eiw^T   + l*s_inh*(1-y_inh)
// s_new = relu(pre); y_new = (s_new + b > 0)
//
// Round 5: split-bf16 3-pass MFMA GEMM (A = Ahi+Alo, B = Bhi+Blo bf16;
// C += AhiBhi + AhiBlo + AloBhi -> ~1e-5 abs error, f32-grade for the proven
// 1e-3 tie-fixup band). 128x128 block tile, 4 waves x (64x64 via 4x4 frags of
// 16x16x32), K-tile 32, LDS [row][40] (pad for bank spread, 80B row = 16B
// aligned for ds_read_b128). B staged transposed in-LDS for iw / eiw-exc
// (packed k-pair ds_write_b32), naturally (negated) for eiw-inh.
// Fixup kernel: unchanged from round 4 (verified), f32-hardcoded.

typedef short bf16x8 __attribute__((ext_vector_type(8)));
typedef unsigned short u16x8 __attribute__((ext_vector_type(8)));
typedef float f32x4 __attribute__((ext_vector_type(4)));

__device__ __forceinline__ float bf2f(unsigned short u) {
  union { unsigned u; float f; } v; v.u = ((unsigned)u) << 16; return v.f;
}
__device__ __forceinline__ unsigned short f2bf(float f) {
  union { float f; unsigned u; } v; v.f = f;
  unsigned x = v.u;
  return (unsigned short)((x + 0x7fffu + ((x >> 16) & 1u)) >> 16);
}
__device__ __forceinline__ void cvt2(float x, unsigned short& hi, unsigned short& lo) {
  unsigned short h = f2bf(x);
  hi = h;
  lo = f2bf(x - bf2f(h));
}

__global__ void ws_zero(int* wscnt) {
  if (threadIdx.x == 0 && blockIdx.x == 0) *wscnt = 0;
}

__global__ __launch_bounds__(256) void eisnu_mfma(
    const float* __restrict__ x_t, const float* __restrict__ y_exc,
    const float* __restrict__ s_exc, const float* __restrict__ y_inh,
    const float* __restrict__ s_inh, const float* __restrict__ iw,
    const float* __restrict__ eiw, const float* __restrict__ bvec,
    const float* __restrict__ lvec, float* __restrict__ out,
    int* wscnt, int* wslist, int cap) {
  __shared__ __align__(16) unsigned short sAhi[128 * 40];
  __shared__ __align__(16) unsigned short sAlo[128 * 40];
  __shared__ __align__(16) unsigned short sBhi[128 * 40];
  __shared__ __align__(16) unsigned short sBlo[128 * 40];

  const int t = threadIdx.x;
  const int n0 = blockIdx.x * 128;
  const int m0 = blockIdx.y * 128;
  const bool exc = n0 < 1024;

  const int l = t & 63, wid = t >> 6;
  const int waveM = wid >> 1, waveN = wid & 1;
  const int col = l & 15, quad = l >> 4;

  // staging maps
  const int am = t >> 1, aks = (t & 1) * 16;  // row-major stage: row, k-seg
  const int kp = t >> 4, lc = t & 15;         // transpose stage: k-pair, lane-col

  f32x4 acc[4][4];
#pragma unroll
  for (int i = 0; i < 4; i++)
#pragma unroll
    for (int j = 0; j < 4; j++) acc[i][j] = f32x4{0.f, 0.f, 0.f, 0.f};

#pragma unroll 1
  for (int p = 0; p < 2; p++) {
    const float* Asrc;
    int lda, K;
    if (p == 0) { Asrc = x_t; lda = 512; K = 512; }
    else        { Asrc = exc ? y_inh : y_exc; lda = 1024; K = 1024; }
    const float* Bsrc = (p == 0) ? iw : eiw;
    const int ldb = (p == 0) ? 2048 : 1024;
    const bool btrans = (p == 0) || exc;       // B accessed by columns -> LDS transpose
    const int ncol = (p == 0) ? n0 : (exc ? n0 : 0);
    const int nrow = btrans ? 0 : (n0 - 1024); // natural-row base (inh)

#pragma unroll 1
    for (int k0 = 0; k0 < K; k0 += 32) {
      // ---- stage A (row-major, coalesced float4) ----
      {
        const float* g = Asrc + (size_t)(m0 + am) * lda + k0 + aks;
        float v[16];
#pragma unroll
        for (int i = 0; i < 4; i++) *(f32x4*)&v[4 * i] = *(const f32x4*)(g + 4 * i);
        unsigned short hi[16], lo[16];
#pragma unroll
        for (int q = 0; q < 16; q++) cvt2(v[q], hi[q], lo[q]);
        u16x8 H0, H1, L0, L1;
#pragma unroll
        for (int q = 0; q < 8; q++) { H0[q] = hi[q]; H1[q] = hi[8 + q]; L0[q] = lo[q]; L1[q] = lo[8 + q]; }
        *(u16x8*)(sAhi + am * 40 + aks) = H0;
        *(u16x8*)(sAhi + am * 40 + aks + 8) = H1;
        *(u16x8*)(sAlo + am * 40 + aks) = L0;
        *(u16x8*)(sAlo + am * 40 + aks + 8) = L1;
      }
      // ---- stage B ----
      if (btrans) {
        // read [k][n] coalesced rows, write [n][k] packed k-pairs
        const float* g = Bsrc + (size_t)(k0 + 2 * kp) * ldb + ncol;
#pragma unroll
        for (int j = 0; j < 8; j++) {
          const int n = 16 * j + lc;
          const float x0 = g[n];
          const float x1 = g[ldb + n];
          unsigned short h0, l0, h1, l1;
          cvt2(x0, h0, l0);
          cvt2(x1, h1, l1);
          ((unsigned*)sBhi)[n * 20 + kp] = (unsigned)h0 | ((unsigned)h1 << 16);
          ((unsigned*)sBlo)[n * 20 + kp] = (unsigned)l0 | ((unsigned)l1 << 16);
        }
      } else {
        // natural rows of eiw, negated
        const float* g = Bsrc + (size_t)(nrow + am) * ldb + k0 + aks;
        float v[16];
#pragma unroll
        for (int i = 0; i < 4; i++) *(f32x4*)&v[4 * i] = *(const f32x4*)(g + 4 * i);
        unsigned short hi[16], lo[16];
#pragma unroll
        for (int q = 0; q < 16; q++) cvt2(-v[q], hi[q], lo[q]);
        u16x8 H0, H1, L0, L1;
#pragma unroll
        for (int q = 0; q < 8; q++) { H0[q] = hi[q]; H1[q] = hi[8 + q]; L0[q] = lo[q]; L1[q] = lo[8 + q]; }
        *(u16x8*)(sBhi + am * 40 + aks) = H0;
        *(u16x8*)(sBhi + am * 40 + aks + 8) = H1;
        *(u16x8*)(sBlo + am * 40 + aks) = L0;
        *(u16x8*)(sBlo + am * 40 + aks + 8) = L1;
      }
      __syncthreads();

      // ---- fragments + 3-pass MFMA ----
      bf16x8 ahi[4], alo[4], bhi[4], blo[4];
#pragma unroll
      for (int mi = 0; mi < 4; mi++) {
        const int off = (waveM * 64 + mi * 16 + col) * 40 + quad * 8;
        ahi[mi] = *(const bf16x8*)(sAhi + off);
        alo[mi] = *(const bf16x8*)(sAlo + off);
      }
#pragma unroll
      for (int ni = 0; ni < 4; ni++) {
        const int off = (waveN * 64 + ni * 16 + col) * 40 + quad * 8;
        bhi[ni] = *(const bf16x8*)(sBhi + off);
        blo[ni] = *(const bf16x8*)(sBlo + off);
      }
#pragma unroll
      for (int mi = 0; mi < 4; mi++)
#pragma unroll
        for (int ni = 0; ni < 4; ni++) {
          acc[mi][ni] = __builtin_amdgcn_mfma_f32_16x16x32_bf16(ahi[mi], bhi[ni], acc[mi][ni], 0, 0, 0);
          acc[mi][ni] = __builtin_amdgcn_mfma_f32_16x16x32_bf16(ahi[mi], blo[ni], acc[mi][ni], 0, 0, 0);
          acc[mi][ni] = __builtin_amdgcn_mfma_f32_16x16x32_bf16(alo[mi], bhi[ni], acc[mi][ni], 0, 0, 0);
        }
      __syncthreads();
    }
  }

  // ---- epilogue (chunk mapping verified round 4) ----
  const float* yE = exc ? y_exc : y_inh;
  const float* sE = exc ? s_exc : s_inh;
  const size_t CH = 8388608ull;
  float* outY = out + (size_t)(exc ? 0 : 2) * CH;
  float* outS = out + (size_t)(exc ? 1 : 3) * CH;

#pragma unroll
  for (int ni = 0; ni < 4; ni++) {
    const int gn = n0 + waveN * 64 + ni * 16 + col;
    const int jn = gn - (exc ? 0 : 1024);
    const float lf = lvec[gn];
    const float bb = bvec[gn];
#pragma unroll
    for (int mi = 0; mi < 4; mi++) {
#pragma unroll
      for (int r = 0; r < 4; r++) {
        const int grow = m0 + waveM * 64 + mi * 16 + quad * 4 + r;
        const size_t idx = (size_t)grow * 1024 + jn;
        const float yv = yE[idx];
        const float sv = sE[idx];
        const float pre = acc[mi][ni][r] + yv + lf * sv * (1.0f - yv);
        const float sn = fmaxf(pre, 0.0f);
        outS[idx] = sn;
        outY[idx] = (sn + bb > 0.0f) ? 1.0f : 0.0f;
        if (cap > 0 && fabsf(pre) < 1e-3f) {
          int slot = atomicAdd(wscnt, 1);
          if (slot < cap) wslist[slot] = (int)idx | ((exc ? 0 : 1) << 24);
        }
      }
    }
  }
}

__global__ __launch_bounds__(256) void eisnu_fixup(
    const float* __restrict__ x_t, const float* __restrict__ y_exc,
    const float* __restrict__ s_exc, const float* __restrict__ y_inh,
    const float* __restrict__ s_inh, const float* __restrict__ iw,
    const float* __restrict__ eiw, const float* __restrict__ bvec,
    const float* __restrict__ lvec, float* __restrict__ out,
    const int* wscnt, const int* wslist, int cap) {
  __shared__ double red[256];
  int count = *wscnt;
  if (count > cap) count = cap;

  for (int it = blockIdx.x; it < count; it += gridDim.x) {
    const int item = wslist[it];
    const int half = (item >> 24) & 1;  // 0 = exc, 1 = inh
    const size_t idx = (size_t)(item & 0xFFFFFF);
    const int bb = (int)(idx >> 10);
    const int j = (int)(idx & 1023);
    const int gcol = j + (half << 10);

    double part = 0.0;
    for (int k = threadIdx.x; k < 512; k += 256)
      part += (double)x_t[(size_t)bb * 512 + k] * (double)iw[(size_t)k * 2048 + gcol];
    if (half == 0) {
      for (int k = threadIdx.x; k < 1024; k += 256)
        part += (double)y_inh[(size_t)bb * 1024 + k] * (double)eiw[(size_t)k * 1024 + j];
    } else {
      for (int k = threadIdx.x; k < 1024; k += 256)
        part -= (double)y_exc[(size_t)bb * 1024 + k] * (double)eiw[(size_t)j * 1024 + k];
    }
    red[threadIdx.x] = part;
    __syncthreads();
    for (int s = 128; s > 0; s >>= 1) {
      if (threadIdx.x < s) red[threadIdx.x] += red[threadIdx.x + s];
      __syncthreads();
    }
    if (threadIdx.x == 0) {
      const float yv = half ? y_inh[idx] : y_exc[idx];
      const float sv = half ? s_inh[idx] : s_exc[idx];
      const double pre = red[0] + (double)yv + (double)lvec[gcol] * (double)sv * (1.0 - (double)yv);
      const double sn = pre > 0.0 ? pre : 0.0;
      const size_t CH = 8388608ull;
      out[(size_t)(half ? 2 : 0) * CH + idx] = (sn + (double)bvec[gcol] > 0.0) ? 1.0f : 0.0f;
      out[(size_t)(half ? 3 : 1) * CH + idx] = (float)sn;
    }
    __syncthreads();
  }
}

extern "C" void kernel_launch(void* const* d_in, const int* in_sizes, int n_in,
                              void* d_out, int out_size, void* d_ws, size_t ws_size,
                              hipStream_t stream) {
  const float* x_t   = (const float*)d_in[0];
  const float* y_exc = (const float*)d_in[1];
  const float* s_exc = (const float*)d_in[2];
  const float* y_inh = (const float*)d_in[3];
  const float* s_inh = (const float*)d_in[4];
  const float* iw    = (const float*)d_in[5];
  const float* eiw   = (const float*)d_in[6];
  const float* b     = (const float*)d_in[7];
  const float* lv    = (const float*)d_in[8];
  float* out = (float*)d_out;

  int* wscnt = (int*)d_ws;
  int* wslist = wscnt ? wscnt + 2 : nullptr;
  const int cap = (d_ws != nullptr && ws_size >= (1u << 20)) ? 65536 : 0;

  if (cap > 0) ws_zero<<<1, 64, 0, stream>>>(wscnt);
  eisnu_mfma<<<dim3(16, 64), 256, 0, stream>>>(
      x_t, y_exc, s_exc, y_inh, s_inh, iw, eiw, b, lv, out, wscnt, wslist, cap);
  if (cap > 0)
    eisnu_fixup<<<dim3(256), 256, 0, stream>>>(
        x_t, y_exc, s_exc, y_inh, s_inh, iw, eiw, b, lv, out, wscnt, wslist, cap);
}